// Round 3
// baseline (559.405 us; speedup 1.0000x reference)
//
#include <hip/hip_runtime.h>

// GraphConv 3-layer GCN: N=100000 nodes, E=1280000 edges; dims 128->64->64->40.
constexpr int NN = 100000;
constexpr int NE = 1280000;
constexpr int NP = 100352;       // padded N (= 98 * 1024)
constexpr int NBLK = NP / 1024;  // 98 scan chunks
constexpr int HB = 48;           // private histogram copies (one per block)
constexpr int EPB = (NE + HB - 1) / HB;  // edges per hist/fill block

// ---------------------------------------------------------------------------
// Privatized degree histograms. Each block owns priv_in[b][*], priv_out[b][*]
// and updates them with WORKGROUP-scope atomics -> RMW stays in the local
// XCD L2 (no cross-XCD coherence write-through). Copies merged afterwards.
// ---------------------------------------------------------------------------
__global__ __launch_bounds__(1024) void hist2_kernel(
    const int* __restrict__ src, const int* __restrict__ dst,
    int* __restrict__ priv_out, int* __restrict__ priv_in) {
  int b = blockIdx.x, t = threadIdx.x;
  int* pin  = priv_in  + (size_t)b * NP;
  int* pout = priv_out + (size_t)b * NP;
  for (int i = t; i < NP; i += 1024) { pin[i] = 0; pout[i] = 0; }
  __syncthreads();
  int beg = b * EPB, end = min(beg + EPB, NE);
  for (int e = beg + t; e < end; e += 1024) {
    __hip_atomic_fetch_add(&pin[dst[e]], 1, __ATOMIC_RELAXED,
                           __HIP_MEMORY_SCOPE_WORKGROUP);
    __hip_atomic_fetch_add(&pout[src[e]], 1, __ATOMIC_RELAXED,
                           __HIP_MEMORY_SCOPE_WORKGROUP);
  }
}

// Column-wise merge of the HB copies: cnt_in[n] = sum_b priv_in[b][n], and
// priv_in[b][n] <- exclusive running sum (per-block base offset within node
// n's CSR segment, before adding row_ptr). Also computes both norms.
__global__ __launch_bounds__(256) void merge_scan_kernel(
    int* __restrict__ priv_out, int* __restrict__ priv_in,
    int* __restrict__ cnt_in, float* __restrict__ norm_out,
    float* __restrict__ norm_in) {
  int n = blockIdx.x * 256 + threadIdx.x;
  if (n >= NP) return;
  int run = 0;
#pragma unroll 8
  for (int b = 0; b < HB; ++b) {
    size_t idx = (size_t)b * NP + n;
    int c = priv_in[idx];
    priv_in[idx] = run;
    run += c;
  }
  cnt_in[n] = run;
  int s = 0;
#pragma unroll 8
  for (int b = 0; b < HB; ++b) s += priv_out[(size_t)b * NP + n];
  if (n < NN) {
    norm_in[n]  = rsqrtf(fmaxf((float)run, 1.0f));
    norm_out[n] = rsqrtf(fmaxf((float)s, 1.0f));
  }
}

// ---------------------------------------------------------------------------
// Two-level exclusive scan of cnt_in -> row_ptr
// ---------------------------------------------------------------------------
__global__ __launch_bounds__(256) void chunk_sum_kernel(
    const int* __restrict__ cnt, int* __restrict__ partial) {
  int t = threadIdx.x;
  int base = blockIdx.x * 1024 + t * 4;
  int s = 0;
#pragma unroll
  for (int j = 0; j < 4; ++j) {
    int gi = base + j;
    s += (gi < NN) ? cnt[gi] : 0;
  }
  __shared__ int r[256];
  r[t] = s;
  __syncthreads();
  for (int off = 128; off > 0; off >>= 1) {
    if (t < off) r[t] += r[t + off];
    __syncthreads();
  }
  if (t == 0) partial[blockIdx.x] = r[0];
}

__global__ __launch_bounds__(128) void partial_scan_kernel(int* __restrict__ partial) {
  int t = threadIdx.x;
  int v = (t < NBLK) ? partial[t] : 0;
  __shared__ int s[128];
  s[t] = v;
  __syncthreads();
  for (int off = 1; off < 128; off <<= 1) {
    int add = (t >= off) ? s[t - off] : 0;
    __syncthreads();
    s[t] += add;
    __syncthreads();
  }
  if (t < NBLK) partial[t] = s[t] - v;  // exclusive
}

__global__ __launch_bounds__(256) void chunk_scan_kernel(
    const int* __restrict__ cnt, const int* __restrict__ partial,
    int* __restrict__ row_ptr) {
  int t = threadIdx.x;
  int base = blockIdx.x * 1024 + t * 4;
  int c[4];
#pragma unroll
  for (int j = 0; j < 4; ++j) {
    int gi = base + j;
    c[j] = (gi < NN) ? cnt[gi] : 0;
  }
  int tsum = c[0] + c[1] + c[2] + c[3];
  __shared__ int s[256];
  s[t] = tsum;
  __syncthreads();
  for (int off = 1; off < 256; off <<= 1) {
    int add = (t >= off) ? s[t - off] : 0;
    __syncthreads();
    s[t] += add;
    __syncthreads();
  }
  int run = s[t] - tsum + partial[blockIdx.x];
#pragma unroll
  for (int j = 0; j < 4; ++j) {
    int gi = base + j;
    if (gi <= NN) row_ptr[gi] = run;
    run += c[j];
  }
}

// CSR fill: block b re-reads its edge range; slot = row_ptr[d] + base[b][d]
// + local rank, local rank via WORKGROUP-scope atomic on the private base
// (in-place cursor). No device-scope atomics anywhere.
__global__ __launch_bounds__(1024) void fill2_kernel(
    const int* __restrict__ src, const int* __restrict__ dst,
    const int* __restrict__ row_ptr, int* __restrict__ priv_in,
    int* __restrict__ csr_src) {
  int b = blockIdx.x, t = threadIdx.x;
  int* pin = priv_in + (size_t)b * NP;
  int beg = b * EPB, end = min(beg + EPB, NE);
  for (int e = beg + t; e < end; e += 1024) {
    int d = dst[e];
    int local = __hip_atomic_fetch_add(&pin[d], 1, __ATOMIC_RELAXED,
                                       __HIP_MEMORY_SCOPE_WORKGROUP);
    csr_src[row_ptr[d] + local] = src[e];
  }
}

// ---------------------------------------------------------------------------
// GEMM:  out[row, :] = PRE(in[row, :]) @ W     (PRE = *norm_out for layer 0)
// 64x64 tile, K-chunks of 32, x staged transposed in LDS (stride 68).
// ---------------------------------------------------------------------------
template <int K, int COLS, bool SCALE>
__global__ __launch_bounds__(256) void gemm_kernel(
    const float* __restrict__ in, const float* __restrict__ W,
    const float* __restrict__ norm_out, float* __restrict__ out) {
  constexpr int KC = 32;
  constexpr int XS = 68;
  __shared__ float Wl[K][64];
  __shared__ float xt[KC][XS];

  const int tid = threadIdx.x;
  for (int i = tid; i < K * 64; i += 256) {
    int k = i >> 6, c = i & 63;
    Wl[k][c] = (c < COLS) ? W[k * COLS + c] : 0.0f;
  }

  const int tc = tid & 15;
  const int tr = tid >> 4;
  const int row0 = blockIdx.x * 64;

  float acc[4][4] = {};

  for (int kc = 0; kc < K; kc += KC) {
#pragma unroll
    for (int i = 0; i < 8; ++i) {
      int elem = i * 256 + tid;
      int r = elem >> 5;
      int kk = elem & 31;
      int grow = row0 + r;
      float v = 0.0f;
      if (grow < NN) {
        v = in[grow * K + kc + kk];
        if constexpr (SCALE) v *= norm_out[grow];
      }
      xt[kk][r] = v;
    }
    __syncthreads();
#pragma unroll
    for (int kk = 0; kk < KC; ++kk) {
      float4 xv = *(const float4*)&xt[kk][4 * tr];
      float4 wv = *(const float4*)&Wl[kc + kk][4 * tc];
      float xa[4] = {xv.x, xv.y, xv.z, xv.w};
      float wa[4] = {wv.x, wv.y, wv.z, wv.w};
#pragma unroll
      for (int r = 0; r < 4; ++r)
#pragma unroll
        for (int c = 0; c < 4; ++c)
          acc[r][c] = fmaf(xa[r], wa[c], acc[r][c]);
    }
    __syncthreads();
  }

#pragma unroll
  for (int r = 0; r < 4; ++r) {
    int grow = row0 + 4 * tr + r;
    if (grow < NN) {
#pragma unroll
      for (int c = 0; c < 4; ++c) {
        int col = 4 * tc + c;
        if (col < COLS) out[grow * COLS + col] = acc[r][c];
      }
    }
  }
}

// ---------------------------------------------------------------------------
// CSR gather aggregation, one wave per node, lane = feature.
// RELU mode:  out = relu(acc*norm_in + bias) * norm_out   (feeds next GEMM)
// !RELU:      out = acc*norm_in + bias                    (final output)
// ---------------------------------------------------------------------------
template <int C, bool RELU>
__global__ __launch_bounds__(256) void gather_kernel(
    const float* __restrict__ m, const int* __restrict__ row_ptr,
    const int* __restrict__ csr_src, const float* __restrict__ norm_in,
    const float* __restrict__ norm_out, const float* __restrict__ bias,
    float* __restrict__ outp) {
  int node = blockIdx.x * 4 + (threadIdx.x >> 6);
  int lane = threadIdx.x & 63;
  if (node >= NN) return;
  int beg = row_ptr[node];
  int end = row_ptr[node + 1];

  float a0 = 0.f, a1 = 0.f, a2 = 0.f, a3 = 0.f;
  int i = beg;
  for (; i + 4 <= end; i += 4) {
    int s0 = csr_src[i], s1 = csr_src[i + 1], s2 = csr_src[i + 2], s3 = csr_src[i + 3];
    if (lane < C) {
      a0 += m[s0 * C + lane];
      a1 += m[s1 * C + lane];
      a2 += m[s2 * C + lane];
      a3 += m[s3 * C + lane];
    }
  }
  for (; i < end; ++i) {
    int s = csr_src[i];
    if (lane < C) a0 += m[s * C + lane];
  }
  float acc = (a0 + a1) + (a2 + a3);

  if (lane < C) {
    float v = fmaf(acc, norm_in[node], bias[lane]);
    if constexpr (RELU) v = fmaxf(v, 0.f) * norm_out[node];
    outp[node * C + lane] = v;
  }
}

// ---------------------------------------------------------------------------
extern "C" void kernel_launch(void* const* d_in, const int* in_sizes, int n_in,
                              void* d_out, int out_size, void* d_ws, size_t ws_size,
                              hipStream_t stream) {
  const float* x    = (const float*)d_in[0];
  const float* W0   = (const float*)d_in[1];
  const float* b0   = (const float*)d_in[2];
  const float* W1   = (const float*)d_in[3];
  const float* b1   = (const float*)d_in[4];
  const float* W2   = (const float*)d_in[5];
  const float* b2   = (const float*)d_in[6];
  const int*   esrc = (const int*)d_in[7];
  const int*   edst = (const int*)d_in[8];
  float* out = (float*)d_out;

  // Workspace (4B units):
  //   norm_out[NP] norm_in[NP] row_ptr[NP] cnt_in[NP] partial[128]
  //   csr_src[NE] m[NN*64] h[NN*64]                       total ~57.6 MB
  // priv_in/priv_out (HB copies each, 38.5 MB) alias the m/h region — they
  // are dead before the first GEMM writes m.
  float* f        = (float*)d_ws;
  float* norm_out = f;
  float* norm_in  = f + NP;
  int*   row_ptr  = (int*)(f + 2 * NP);
  int*   cnt_in   = row_ptr + NP;
  int*   partial  = cnt_in + NP;
  int*   csr_src  = partial + 128;
  float* m        = (float*)(csr_src + NE);
  float* h        = m + NN * 64;
  int*   priv_in  = (int*)m;                    // HB*NP ints
  int*   priv_out = priv_in + (size_t)HB * NP;  // HB*NP ints

  // --- CSR build (dst-sorted) + norms: no device-scope atomics ---
  hist2_kernel<<<HB, 1024, 0, stream>>>(esrc, edst, priv_out, priv_in);
  merge_scan_kernel<<<(NP + 255) / 256, 256, 0, stream>>>(
      priv_out, priv_in, cnt_in, norm_out, norm_in);
  chunk_sum_kernel<<<NBLK, 256, 0, stream>>>(cnt_in, partial);
  partial_scan_kernel<<<1, 128, 0, stream>>>(partial);
  chunk_scan_kernel<<<NBLK, 256, 0, stream>>>(cnt_in, partial, row_ptr);
  fill2_kernel<<<HB, 1024, 0, stream>>>(esrc, edst, row_ptr, priv_in, csr_src);

  const int gb = (NN + 63) / 64;
  const int gg = (NN + 3) / 4;

  // Layer 0: m = (x*norm_out) @ W0 ; h = relu(agg*norm_in + b0)*norm_out
  gemm_kernel<128, 64, true><<<gb, 256, 0, stream>>>(x, W0, norm_out, m);
  gather_kernel<64, true><<<gg, 256, 0, stream>>>(m, row_ptr, csr_src, norm_in, norm_out, b0, h);

  // Layer 1: m = h @ W1 ; h = relu(agg*norm_in + b1)*norm_out
  gemm_kernel<64, 64, false><<<gb, 256, 0, stream>>>(h, W1, nullptr, m);
  gather_kernel<64, true><<<gg, 256, 0, stream>>>(m, row_ptr, csr_src, norm_in, norm_out, b1, h);

  // Layer 2: m = h @ W2 (40 cols) ; out = agg*norm_in + b2
  gemm_kernel<64, 40, false><<<gb, 256, 0, stream>>>(h, W2, nullptr, m);
  gather_kernel<40, false><<<gg, 256, 0, stream>>>(m, row_ptr, csr_src, norm_in, norm_out, b2, out);
}

// Round 4
// 515.981 us; speedup vs baseline: 1.0842x; 1.0842x over previous
//
#include <hip/hip_runtime.h>

// GraphConv 3-layer GCN: N=100000 nodes, E=1280000 edges; dims 128->64->64->40.
constexpr int NN = 100000;
constexpr int NE = 1280000;
constexpr int NP = 100352;       // padded N (= 98 * 1024)
constexpr int NBLK = NP / 1024;  // 98 scan chunks

// LDS-segmented histogram geometry
constexpr int SEGSZ = 16384;                  // 64 KB of int bins per block
constexpr int NSEG = 7;                       // 7*16384 = 114688 >= NP
constexpr int NCHUNK = 32;                    // edge chunks
constexpr int CHSZ = NE / NCHUNK;             // 40000 (exact)

// ---------------------------------------------------------------------------
// Histogram of vals[] (node ids) into partial[c][n], via LDS bins.
// Block (s,c): LDS-count chunk c's values that fall in segment s, then dump.
// No global atomics anywhere; edge chunks are read coalesced and stay L2-hot.
// ---------------------------------------------------------------------------
__global__ __launch_bounds__(256) void hist_lds_kernel(
    const int* __restrict__ vals, int* __restrict__ partial) {
  __shared__ int hcnt[SEGSZ];
  const int bi = blockIdx.x;
  const int s = bi % NSEG, c = bi / NSEG;
  const int t = threadIdx.x;
  for (int i = t; i < SEGSZ; i += 256) hcnt[i] = 0;
  __syncthreads();
  const int lo = s * SEGSZ, hi = lo + SEGSZ;
  const int beg = c * CHSZ, end = beg + CHSZ;
  for (int e = beg + t; e < end; e += 256) {
    int v = vals[e];
    if (v >= lo && v < hi) atomicAdd(&hcnt[v - lo], 1);  // LDS atomic
  }
  __syncthreads();
  int* p = partial + (size_t)c * NP;
  for (int i = t; i < SEGSZ; i += 256) {
    int n = lo + i;
    if (n < NP) p[n] = hcnt[i];
  }
}

// ---------------------------------------------------------------------------
// Merge the 32 chunk-partials per node: cnt_in = sum, partial_in <- exclusive
// chunk-prefix (in place, consumed by fill), norms from both degree sums.
// ---------------------------------------------------------------------------
__global__ __launch_bounds__(256) void merge_kernel(
    int* __restrict__ pin, const int* __restrict__ pout,
    int* __restrict__ cnt_in, float* __restrict__ norm_out,
    float* __restrict__ norm_in) {
  int n = blockIdx.x * 256 + threadIdx.x;
  if (n >= NP) return;
  int run = 0;
#pragma unroll 8
  for (int c = 0; c < NCHUNK; ++c) {
    size_t idx = (size_t)c * NP + n;
    int v = pin[idx];
    pin[idx] = run;
    run += v;
  }
  cnt_in[n] = run;
  int s = 0;
#pragma unroll 8
  for (int c = 0; c < NCHUNK; ++c) s += pout[(size_t)c * NP + n];
  if (n < NN) {
    norm_in[n]  = rsqrtf(fmaxf((float)run, 1.0f));
    norm_out[n] = rsqrtf(fmaxf((float)s, 1.0f));
  }
}

// ---------------------------------------------------------------------------
// Two-level exclusive scan of cnt_in -> row_ptr
// ---------------------------------------------------------------------------
__global__ __launch_bounds__(256) void chunk_sum_kernel(
    const int* __restrict__ cnt, int* __restrict__ partial) {
  int t = threadIdx.x;
  int base = blockIdx.x * 1024 + t * 4;
  int s = 0;
#pragma unroll
  for (int j = 0; j < 4; ++j) {
    int gi = base + j;
    s += (gi < NN) ? cnt[gi] : 0;
  }
  __shared__ int r[256];
  r[t] = s;
  __syncthreads();
  for (int off = 128; off > 0; off >>= 1) {
    if (t < off) r[t] += r[t + off];
    __syncthreads();
  }
  if (t == 0) partial[blockIdx.x] = r[0];
}

__global__ __launch_bounds__(128) void partial_scan_kernel(int* __restrict__ partial) {
  int t = threadIdx.x;
  int v = (t < NBLK) ? partial[t] : 0;
  __shared__ int s[128];
  s[t] = v;
  __syncthreads();
  for (int off = 1; off < 128; off <<= 1) {
    int add = (t >= off) ? s[t - off] : 0;
    __syncthreads();
    s[t] += add;
    __syncthreads();
  }
  if (t < NBLK) partial[t] = s[t] - v;  // exclusive
}

__global__ __launch_bounds__(256) void chunk_scan_kernel(
    const int* __restrict__ cnt, const int* __restrict__ partial,
    int* __restrict__ row_ptr) {
  int t = threadIdx.x;
  int base = blockIdx.x * 1024 + t * 4;
  int c[4];
#pragma unroll
  for (int j = 0; j < 4; ++j) {
    int gi = base + j;
    c[j] = (gi < NN) ? cnt[gi] : 0;
  }
  int tsum = c[0] + c[1] + c[2] + c[3];
  __shared__ int s[256];
  s[t] = tsum;
  __syncthreads();
  for (int off = 1; off < 256; off <<= 1) {
    int add = (t >= off) ? s[t - off] : 0;
    __syncthreads();
    s[t] += add;
    __syncthreads();
  }
  int run = s[t] - tsum + partial[blockIdx.x];
#pragma unroll
  for (int j = 0; j < 4; ++j) {
    int gi = base + j;
    if (gi <= NN) row_ptr[gi] = run;
    run += c[j];
  }
}

// ---------------------------------------------------------------------------
// CSR fill via LDS cursors: block (s,c) preloads row_ptr[n]+prefix[c][n] for
// its segment, then claims slots with LDS atomicAdd. No device atomics.
// ---------------------------------------------------------------------------
__global__ __launch_bounds__(256) void fill_lds_kernel(
    const int* __restrict__ src, const int* __restrict__ dst,
    const int* __restrict__ row_ptr, const int* __restrict__ pin,
    int* __restrict__ csr_src) {
  __shared__ int cur[SEGSZ];
  const int bi = blockIdx.x;
  const int s = bi % NSEG, c = bi / NSEG;
  const int t = threadIdx.x;
  const int lo = s * SEGSZ, hi = lo + SEGSZ;
  const int* base = pin + (size_t)c * NP;
  for (int i = t; i < SEGSZ; i += 256) {
    int n = lo + i;
    cur[i] = (n < NN) ? (row_ptr[n] + base[n]) : 0;
  }
  __syncthreads();
  const int beg = c * CHSZ, end = beg + CHSZ;
  for (int e = beg + t; e < end; e += 256) {
    int d = dst[e];
    if (d >= lo && d < hi) {
      int pos = atomicAdd(&cur[d - lo], 1);  // LDS atomic
      csr_src[pos] = src[e];
    }
  }
}

// ---------------------------------------------------------------------------
// GEMM:  out[row, :] = PRE(in[row, :]) @ W     (PRE = *norm_out for layer 0)
// 64x64 tile, K-chunks of 32, x staged transposed in LDS (stride 68).
// ---------------------------------------------------------------------------
template <int K, int COLS, bool SCALE>
__global__ __launch_bounds__(256) void gemm_kernel(
    const float* __restrict__ in, const float* __restrict__ W,
    const float* __restrict__ norm_out, float* __restrict__ out) {
  constexpr int KC = 32;
  constexpr int XS = 68;
  __shared__ float Wl[K][64];
  __shared__ float xt[KC][XS];

  const int tid = threadIdx.x;
  for (int i = tid; i < K * 64; i += 256) {
    int k = i >> 6, c = i & 63;
    Wl[k][c] = (c < COLS) ? W[k * COLS + c] : 0.0f;
  }

  const int tc = tid & 15;
  const int tr = tid >> 4;
  const int row0 = blockIdx.x * 64;

  float acc[4][4] = {};

  for (int kc = 0; kc < K; kc += KC) {
#pragma unroll
    for (int i = 0; i < 8; ++i) {
      int elem = i * 256 + tid;
      int r = elem >> 5;
      int kk = elem & 31;
      int grow = row0 + r;
      float v = 0.0f;
      if (grow < NN) {
        v = in[grow * K + kc + kk];
        if constexpr (SCALE) v *= norm_out[grow];
      }
      xt[kk][r] = v;
    }
    __syncthreads();
#pragma unroll
    for (int kk = 0; kk < KC; ++kk) {
      float4 xv = *(const float4*)&xt[kk][4 * tr];
      float4 wv = *(const float4*)&Wl[kc + kk][4 * tc];
      float xa[4] = {xv.x, xv.y, xv.z, xv.w};
      float wa[4] = {wv.x, wv.y, wv.z, wv.w};
#pragma unroll
      for (int r = 0; r < 4; ++r)
#pragma unroll
        for (int c = 0; c < 4; ++c)
          acc[r][c] = fmaf(xa[r], wa[c], acc[r][c]);
    }
    __syncthreads();
  }

#pragma unroll
  for (int r = 0; r < 4; ++r) {
    int grow = row0 + 4 * tr + r;
    if (grow < NN) {
#pragma unroll
      for (int c = 0; c < 4; ++c) {
        int col = 4 * tc + c;
        if (col < COLS) out[grow * COLS + col] = acc[r][c];
      }
    }
  }
}

// ---------------------------------------------------------------------------
// CSR gather aggregation, one wave per node, lane = feature.
// RELU mode:  out = relu(acc*norm_in + bias) * norm_out   (feeds next GEMM)
// !RELU:      out = acc*norm_in + bias                    (final output)
// ---------------------------------------------------------------------------
template <int C, bool RELU>
__global__ __launch_bounds__(256) void gather_kernel(
    const float* __restrict__ m, const int* __restrict__ row_ptr,
    const int* __restrict__ csr_src, const float* __restrict__ norm_in,
    const float* __restrict__ norm_out, const float* __restrict__ bias,
    float* __restrict__ outp) {
  int node = blockIdx.x * 4 + (threadIdx.x >> 6);
  int lane = threadIdx.x & 63;
  if (node >= NN) return;
  int beg = row_ptr[node];
  int end = row_ptr[node + 1];

  float a0 = 0.f, a1 = 0.f, a2 = 0.f, a3 = 0.f;
  int i = beg;
  for (; i + 4 <= end; i += 4) {
    int s0 = csr_src[i], s1 = csr_src[i + 1], s2 = csr_src[i + 2], s3 = csr_src[i + 3];
    if (lane < C) {
      a0 += m[s0 * C + lane];
      a1 += m[s1 * C + lane];
      a2 += m[s2 * C + lane];
      a3 += m[s3 * C + lane];
    }
  }
  for (; i < end; ++i) {
    int s = csr_src[i];
    if (lane < C) a0 += m[s * C + lane];
  }
  float acc = (a0 + a1) + (a2 + a3);

  if (lane < C) {
    float v = fmaf(acc, norm_in[node], bias[lane]);
    if constexpr (RELU) v = fmaxf(v, 0.f) * norm_out[node];
    outp[node * C + lane] = v;
  }
}

// ---------------------------------------------------------------------------
extern "C" void kernel_launch(void* const* d_in, const int* in_sizes, int n_in,
                              void* d_out, int out_size, void* d_ws, size_t ws_size,
                              hipStream_t stream) {
  const float* x    = (const float*)d_in[0];
  const float* W0   = (const float*)d_in[1];
  const float* b0   = (const float*)d_in[2];
  const float* W1   = (const float*)d_in[3];
  const float* b1   = (const float*)d_in[4];
  const float* W2   = (const float*)d_in[5];
  const float* b2   = (const float*)d_in[6];
  const int*   esrc = (const int*)d_in[7];
  const int*   edst = (const int*)d_in[8];
  float* out = (float*)d_out;

  // Workspace (4B units):
  //   norm_out[NP] norm_in[NP] row_ptr[NP] cnt_in[NP] partial[128]
  //   csr_src[NE] m[NN*64] h[NN*64]                      (~57.6 MB)
  // CSR-build transients alias m/h (dead until gemm0):
  //   partial_in = m (NCHUNK*NP ints, 12.85 MB), partial_out = h.
  float* f        = (float*)d_ws;
  float* norm_out = f;
  float* norm_in  = f + NP;
  int*   row_ptr  = (int*)(f + 2 * NP);
  int*   cnt_in   = row_ptr + NP;
  int*   partial  = cnt_in + NP;
  int*   csr_src  = partial + 128;
  float* m        = (float*)(csr_src + NE);
  float* h        = m + NN * 64;
  int*   pin      = (int*)m;
  int*   pout     = (int*)h;

  // --- CSR build (dst-sorted) + norms: zero global atomics ---
  hist_lds_kernel<<<NSEG * NCHUNK, 256, 0, stream>>>(edst, pin);
  hist_lds_kernel<<<NSEG * NCHUNK, 256, 0, stream>>>(esrc, pout);
  merge_kernel<<<(NP + 255) / 256, 256, 0, stream>>>(pin, pout, cnt_in, norm_out, norm_in);
  chunk_sum_kernel<<<NBLK, 256, 0, stream>>>(cnt_in, partial);
  partial_scan_kernel<<<1, 128, 0, stream>>>(partial);
  chunk_scan_kernel<<<NBLK, 256, 0, stream>>>(cnt_in, partial, row_ptr);
  fill_lds_kernel<<<NSEG * NCHUNK, 256, 0, stream>>>(esrc, edst, row_ptr, pin, csr_src);

  const int gb = (NN + 63) / 64;
  const int gg = (NN + 3) / 4;

  // Layer 0: m = (x*norm_out) @ W0 ; h = relu(agg*norm_in + b0)*norm_out
  gemm_kernel<128, 64, true><<<gb, 256, 0, stream>>>(x, W0, norm_out, m);
  gather_kernel<64, true><<<gg, 256, 0, stream>>>(m, row_ptr, csr_src, norm_in, norm_out, b0, h);

  // Layer 1: m = h @ W1 ; h = relu(agg*norm_in + b1)*norm_out
  gemm_kernel<64, 64, false><<<gb, 256, 0, stream>>>(h, W1, nullptr, m);
  gather_kernel<64, true><<<gg, 256, 0, stream>>>(m, row_ptr, csr_src, norm_in, norm_out, b1, h);

  // Layer 2: m = h @ W2 (40 cols) ; out = agg*norm_in + b2
  gemm_kernel<64, 40, false><<<gb, 256, 0, stream>>>(h, W2, nullptr, m);
  gather_kernel<40, false><<<gg, 256, 0, stream>>>(m, row_ptr, csr_src, norm_in, norm_out, b2, out);
}

// Round 5
// 349.593 us; speedup vs baseline: 1.6002x; 1.4759x over previous
//
#include <hip/hip_runtime.h>

// GraphConv 3-layer GCN: N=100000 nodes, E=1280000 edges; dims 128->64->64->40.
constexpr int NN = 100000;
constexpr int NE = 1280000;
constexpr int NP = 100352;       // padded N (= 98 * 1024)
constexpr int NBLK = NP / 1024;  // 98 scan chunks

// LDS-segmented histogram geometry.
// 64 KB LDS/block + 1024-thread blocks -> 2 blocks/CU = 32 waves/CU (full).
constexpr int SEGSZ = 16384;                  // 64 KB of int bins per block
constexpr int NSEG = 7;                       // 7*16384 = 114688 >= NN
constexpr int NCHUNK = 64;                    // edge chunks
constexpr int CHSZ = NE / NCHUNK;             // 20000 (exact)

// ---------------------------------------------------------------------------
// Histogram of vals[] (node ids) into partial[c][n] (stride NN), via LDS bins.
// Block (s,c): count chunk c's values falling in segment s, then dump.
// ---------------------------------------------------------------------------
__global__ __launch_bounds__(1024) void hist_lds_kernel(
    const int* __restrict__ vals, int* __restrict__ partial) {
  __shared__ int hcnt[SEGSZ];
  const int s = blockIdx.x % NSEG, c = blockIdx.x / NSEG;
  const int t = threadIdx.x;
#pragma unroll 4
  for (int i = t; i < SEGSZ; i += 1024) hcnt[i] = 0;
  __syncthreads();
  const int lo = s * SEGSZ;
  const int beg = c * CHSZ;
  for (int e = beg + t; e < beg + CHSZ; e += 1024) {
    unsigned v = (unsigned)(vals[e] - lo);
    if (v < (unsigned)SEGSZ) atomicAdd(&hcnt[v], 1);  // LDS atomic
  }
  __syncthreads();
  int* p = partial + (size_t)c * NN;
#pragma unroll 4
  for (int i = t; i < SEGSZ; i += 1024) {
    int n = lo + i;
    if (n < NN) p[n] = hcnt[i];
  }
}

// ---------------------------------------------------------------------------
// Merge the chunk-partials per node: cnt_in = sum, pin <- exclusive chunk
// prefix (in place, consumed by fill), norms from both degree sums.
// ---------------------------------------------------------------------------
__global__ __launch_bounds__(256) void merge_kernel(
    int* __restrict__ pin, const int* __restrict__ pout,
    int* __restrict__ cnt_in, float* __restrict__ norm_out,
    float* __restrict__ norm_in) {
  int n = blockIdx.x * 256 + threadIdx.x;
  if (n >= NN) return;
  int run = 0;
#pragma unroll 8
  for (int c = 0; c < NCHUNK; ++c) {
    size_t idx = (size_t)c * NN + n;
    int v = pin[idx];
    pin[idx] = run;
    run += v;
  }
  cnt_in[n] = run;
  int s = 0;
#pragma unroll 8
  for (int c = 0; c < NCHUNK; ++c) s += pout[(size_t)c * NN + n];
  norm_in[n]  = rsqrtf(fmaxf((float)run, 1.0f));
  norm_out[n] = rsqrtf(fmaxf((float)s, 1.0f));
}

// ---------------------------------------------------------------------------
// Two-level exclusive scan of cnt_in -> row_ptr
// ---------------------------------------------------------------------------
__global__ __launch_bounds__(256) void chunk_sum_kernel(
    const int* __restrict__ cnt, int* __restrict__ partial) {
  int t = threadIdx.x;
  int base = blockIdx.x * 1024 + t * 4;
  int s = 0;
#pragma unroll
  for (int j = 0; j < 4; ++j) {
    int gi = base + j;
    s += (gi < NN) ? cnt[gi] : 0;
  }
  __shared__ int r[256];
  r[t] = s;
  __syncthreads();
  for (int off = 128; off > 0; off >>= 1) {
    if (t < off) r[t] += r[t + off];
    __syncthreads();
  }
  if (t == 0) partial[blockIdx.x] = r[0];
}

__global__ __launch_bounds__(128) void partial_scan_kernel(int* __restrict__ partial) {
  int t = threadIdx.x;
  int v = (t < NBLK) ? partial[t] : 0;
  __shared__ int s[128];
  s[t] = v;
  __syncthreads();
  for (int off = 1; off < 128; off <<= 1) {
    int add = (t >= off) ? s[t - off] : 0;
    __syncthreads();
    s[t] += add;
    __syncthreads();
  }
  if (t < NBLK) partial[t] = s[t] - v;  // exclusive
}

__global__ __launch_bounds__(256) void chunk_scan_kernel(
    const int* __restrict__ cnt, const int* __restrict__ partial,
    int* __restrict__ row_ptr) {
  int t = threadIdx.x;
  int base = blockIdx.x * 1024 + t * 4;
  int c[4];
#pragma unroll
  for (int j = 0; j < 4; ++j) {
    int gi = base + j;
    c[j] = (gi < NN) ? cnt[gi] : 0;
  }
  int tsum = c[0] + c[1] + c[2] + c[3];
  __shared__ int s[256];
  s[t] = tsum;
  __syncthreads();
  for (int off = 1; off < 256; off <<= 1) {
    int add = (t >= off) ? s[t - off] : 0;
    __syncthreads();
    s[t] += add;
    __syncthreads();
  }
  int run = s[t] - tsum + partial[blockIdx.x];
#pragma unroll
  for (int j = 0; j < 4; ++j) {
    int gi = base + j;
    if (gi <= NN) row_ptr[gi] = run;
    run += c[j];
  }
}

// ---------------------------------------------------------------------------
// CSR fill via LDS cursors: block (s,c) preloads row_ptr[n]+prefix[c][n] for
// its segment, then claims slots with LDS atomicAdd. No device atomics.
// ---------------------------------------------------------------------------
__global__ __launch_bounds__(1024) void fill_lds_kernel(
    const int* __restrict__ src, const int* __restrict__ dst,
    const int* __restrict__ row_ptr, const int* __restrict__ pin,
    int* __restrict__ csr_src) {
  __shared__ int cur[SEGSZ];
  const int s = blockIdx.x % NSEG, c = blockIdx.x / NSEG;
  const int t = threadIdx.x;
  const int lo = s * SEGSZ;
  const int* base = pin + (size_t)c * NN;
#pragma unroll 4
  for (int i = t; i < SEGSZ; i += 1024) {
    int n = lo + i;
    cur[i] = (n < NN) ? (row_ptr[n] + base[n]) : 0;
  }
  __syncthreads();
  const int beg = c * CHSZ;
  for (int e = beg + t; e < beg + CHSZ; e += 1024) {
    unsigned d = (unsigned)(dst[e] - lo);
    if (d < (unsigned)SEGSZ) {
      int pos = atomicAdd(&cur[d], 1);  // LDS atomic
      csr_src[pos] = src[e];
    }
  }
}

// ---------------------------------------------------------------------------
// GEMM:  out[row, :] = PRE(in[row, :]) @ W     (PRE = *norm_out for layer 0)
// 64x64 tile, K-chunks of 32, x staged transposed in LDS (stride 68).
// ---------------------------------------------------------------------------
template <int K, int COLS, bool SCALE>
__global__ __launch_bounds__(256) void gemm_kernel(
    const float* __restrict__ in, const float* __restrict__ W,
    const float* __restrict__ norm_out, float* __restrict__ out) {
  constexpr int KC = 32;
  constexpr int XS = 68;
  __shared__ float Wl[K][64];
  __shared__ float xt[KC][XS];

  const int tid = threadIdx.x;
  for (int i = tid; i < K * 64; i += 256) {
    int k = i >> 6, c = i & 63;
    Wl[k][c] = (c < COLS) ? W[k * COLS + c] : 0.0f;
  }

  const int tc = tid & 15;
  const int tr = tid >> 4;
  const int row0 = blockIdx.x * 64;

  float acc[4][4] = {};

  for (int kc = 0; kc < K; kc += KC) {
#pragma unroll
    for (int i = 0; i < 8; ++i) {
      int elem = i * 256 + tid;
      int r = elem >> 5;
      int kk = elem & 31;
      int grow = row0 + r;
      float v = 0.0f;
      if (grow < NN) {
        v = in[grow * K + kc + kk];
        if constexpr (SCALE) v *= norm_out[grow];
      }
      xt[kk][r] = v;
    }
    __syncthreads();
#pragma unroll
    for (int kk = 0; kk < KC; ++kk) {
      float4 xv = *(const float4*)&xt[kk][4 * tr];
      float4 wv = *(const float4*)&Wl[kc + kk][4 * tc];
      float xa[4] = {xv.x, xv.y, xv.z, xv.w};
      float wa[4] = {wv.x, wv.y, wv.z, wv.w};
#pragma unroll
      for (int r = 0; r < 4; ++r)
#pragma unroll
        for (int c = 0; c < 4; ++c)
          acc[r][c] = fmaf(xa[r], wa[c], acc[r][c]);
    }
    __syncthreads();
  }

#pragma unroll
  for (int r = 0; r < 4; ++r) {
    int grow = row0 + 4 * tr + r;
    if (grow < NN) {
#pragma unroll
      for (int c = 0; c < 4; ++c) {
        int col = 4 * tc + c;
        if (col < COLS) out[grow * COLS + col] = acc[r][c];
      }
    }
  }
}

// ---------------------------------------------------------------------------
// CSR gather, one wave per node, float4 lanes x 4-edge groups.
// lane = eg*16 + fl: edge group eg in [0,4), float4 index fl in [0,16).
// Each wave iteration loads 4 edges' rows (4 x 256B coalesced); cross-group
// reduce via shfl_xor(16/32) at the end.
// RELU: out = relu(acc*norm_in + bias) * norm_out ; else out = acc*norm_in+bias
// ---------------------------------------------------------------------------
template <int C, bool RELU>
__global__ __launch_bounds__(256) void gather_kernel(
    const float* __restrict__ m, const int* __restrict__ row_ptr,
    const int* __restrict__ csr_src, const float* __restrict__ norm_in,
    const float* __restrict__ norm_out, const float* __restrict__ bias,
    float* __restrict__ outp) {
  constexpr int CV = C / 4;  // float4s per row: 16 (C=64), 10 (C=40)
  const int node = blockIdx.x * 4 + (threadIdx.x >> 6);
  const int lane = threadIdx.x & 63;
  if (node >= NN) return;
  const int beg = row_ptr[node];
  const int end = row_ptr[node + 1];
  const int eg = lane >> 4;
  const int fl = lane & 15;
  const float4* m4 = (const float4*)m;

  float4 acc = {0.f, 0.f, 0.f, 0.f};
#pragma unroll 4
  for (int i = beg + eg; i < end; i += 4) {
    int s = csr_src[i];
    if (fl < CV) {
      float4 v = m4[(size_t)s * CV + fl];
      acc.x += v.x; acc.y += v.y; acc.z += v.z; acc.w += v.w;
    }
  }
  acc.x += __shfl_xor(acc.x, 16); acc.y += __shfl_xor(acc.y, 16);
  acc.z += __shfl_xor(acc.z, 16); acc.w += __shfl_xor(acc.w, 16);
  acc.x += __shfl_xor(acc.x, 32); acc.y += __shfl_xor(acc.y, 32);
  acc.z += __shfl_xor(acc.z, 32); acc.w += __shfl_xor(acc.w, 32);

  if (eg == 0 && fl < CV) {
    float ni = norm_in[node];
    float4 b4 = ((const float4*)bias)[fl];
    float4 r;
    r.x = fmaf(acc.x, ni, b4.x);
    r.y = fmaf(acc.y, ni, b4.y);
    r.z = fmaf(acc.z, ni, b4.z);
    r.w = fmaf(acc.w, ni, b4.w);
    if constexpr (RELU) {
      float no = norm_out[node];
      r.x = fmaxf(r.x, 0.f) * no;
      r.y = fmaxf(r.y, 0.f) * no;
      r.z = fmaxf(r.z, 0.f) * no;
      r.w = fmaxf(r.w, 0.f) * no;
    }
    ((float4*)outp)[(size_t)node * CV + fl] = r;
  }
}

// ---------------------------------------------------------------------------
extern "C" void kernel_launch(void* const* d_in, const int* in_sizes, int n_in,
                              void* d_out, int out_size, void* d_ws, size_t ws_size,
                              hipStream_t stream) {
  const float* x    = (const float*)d_in[0];
  const float* W0   = (const float*)d_in[1];
  const float* b0   = (const float*)d_in[2];
  const float* W1   = (const float*)d_in[3];
  const float* b1   = (const float*)d_in[4];
  const float* W2   = (const float*)d_in[5];
  const float* b2   = (const float*)d_in[6];
  const int*   esrc = (const int*)d_in[7];
  const int*   edst = (const int*)d_in[8];
  float* out = (float*)d_out;

  // Workspace (4B units):
  //   norm_out[NP] norm_in[NP] row_ptr[NP] cnt_in[NP] partial[128]
  //   csr_src[NE] m[NN*64] h[NN*64]                      (~57.6 MB)
  // CSR-build transients alias m/h (dead until gemm0):
  //   pin = m (NCHUNK*NN ints = 25.6 MB exactly), pout = h.
  float* f        = (float*)d_ws;
  float* norm_out = f;
  float* norm_in  = f + NP;
  int*   row_ptr  = (int*)(f + 2 * NP);
  int*   cnt_in   = row_ptr + NP;
  int*   partial  = cnt_in + NP;
  int*   csr_src  = partial + 128;
  float* m        = (float*)(csr_src + NE);
  float* h        = m + NN * 64;
  int*   pin      = (int*)m;
  int*   pout     = (int*)h;

  // --- CSR build (dst-sorted) + norms: zero global atomics ---
  hist_lds_kernel<<<NSEG * NCHUNK, 1024, 0, stream>>>(edst, pin);
  hist_lds_kernel<<<NSEG * NCHUNK, 1024, 0, stream>>>(esrc, pout);
  merge_kernel<<<(NN + 255) / 256, 256, 0, stream>>>(pin, pout, cnt_in, norm_out, norm_in);
  chunk_sum_kernel<<<NBLK, 256, 0, stream>>>(cnt_in, partial);
  partial_scan_kernel<<<1, 128, 0, stream>>>(partial);
  chunk_scan_kernel<<<NBLK, 256, 0, stream>>>(cnt_in, partial, row_ptr);
  fill_lds_kernel<<<NSEG * NCHUNK, 1024, 0, stream>>>(esrc, edst, row_ptr, pin, csr_src);

  const int gb = (NN + 63) / 64;
  const int gg = (NN + 3) / 4;

  // Layer 0: m = (x*norm_out) @ W0 ; h = relu(agg*norm_in + b0)*norm_out
  gemm_kernel<128, 64, true><<<gb, 256, 0, stream>>>(x, W0, norm_out, m);
  gather_kernel<64, true><<<gg, 256, 0, stream>>>(m, row_ptr, csr_src, norm_in, norm_out, b0, h);

  // Layer 1: m = h @ W1 ; h = relu(agg*norm_in + b1)*norm_out
  gemm_kernel<64, 64, false><<<gb, 256, 0, stream>>>(h, W1, nullptr, m);
  gather_kernel<64, true><<<gg, 256, 0, stream>>>(m, row_ptr, csr_src, norm_in, norm_out, b1, h);

  // Layer 2: m = h @ W2 (40 cols) ; out = agg*norm_in + b2
  gemm_kernel<64, 40, false><<<gb, 256, 0, stream>>>(h, W2, nullptr, m);
  gather_kernel<40, false><<<gg, 256, 0, stream>>>(m, row_ptr, csr_src, norm_in, norm_out, b2, out);
}